// Round 2
// baseline (528.650 us; speedup 1.0000x reference)
//
#include <hip/hip_runtime.h>
#include <cmath>
#include <cstdint>

// ---------------------------------------------------------------------------
// Plasmodium attention block on MI355X (gfx950).
// Pipeline (all matmuls fp16-MFMA, f32 accumulate, NT layout):
//   0. cast x -> f16; transpose+cast 5 weight matrices -> f16
//   1. h  = tanh(x @ We + be)                [f16]
//   2. q  = x @ Wq + bq ; k = h @ Wk + bk ; v = h @ Wv + bv   [f16]
//   3. per-head L2 norm of q,k,v -> qn,kn,vn [f16]; vT = transpose(v)
//   4. p  = exp(scale * qn·kn^T)  (max-subtraction provably unnecessary:
//          |scores| <= 1/sqrt(512), factor cancels in p·v/sum(p))
//   5. rowsum = sum(p); a = (p @ v) / rowsum   (concat heads)
//   6. y  = LayerNorm(a) [f16];  out = tanh(y @ Wd + bd)  [f32 -> d_out]
//   7. corr = kn @ vn^T  [f32 -> d_out]
// ---------------------------------------------------------------------------

typedef __attribute__((ext_vector_type(8))) _Float16 half8;
typedef __attribute__((ext_vector_type(4))) float f32x4;

typedef __attribute__((address_space(1))) void GV;  // global
typedef __attribute__((address_space(3))) void LV;  // LDS

__device__ __forceinline__ void load_lds16(const _Float16* g, _Float16* l) {
  // dest = wave-uniform base + lane*16B (HW semantic); src is per-lane.
  __builtin_amdgcn_global_load_lds((GV*)g, (LV*)l, 16, 0, 0);
}

// ---------------------------------------------------------------------------
// NT GEMM: C[i,j] = sum_k A[i,k] * B[j,k]   (A:[M,lda], B:[N,ldb] f16 row-major)
// 128x128 tile, BK=32, 4 waves (each 64x64 = 4x4 16x16 fragments).
// EPI: 0 f32 store (+bias)     1 f16 store (+bias)   2 f16 tanh(+bias)
//      3 f16 exp(scale*acc)    4 f32 acc/(rowsum+eps) 5 f32 tanh(+bias)
// ---------------------------------------------------------------------------
template <int EPI>
__global__ __launch_bounds__(256) void gemm_nt(
    const _Float16* __restrict__ A, const _Float16* __restrict__ B,
    void* __restrict__ Cv, int K, int lda, int ldb, int ldc,
    long aZ, long bZ, long cZ,
    const float* __restrict__ bias, float scale,
    const float* __restrict__ rsum, int rsZ) {
  __shared__ _Float16 As[128 * 32];
  __shared__ _Float16 Bs[128 * 32];

  const int z = blockIdx.z;
  A += (long)z * aZ;
  B += (long)z * bZ;

  const int tid = threadIdx.x;
  const int wave = tid >> 6;
  const int lane = tid & 63;
  const int brow = blockIdx.y * 128;
  const int bcol = blockIdx.x * 128;
  const int wr = (wave >> 1) * 64;  // wave row offset in tile
  const int wc = (wave & 1) * 64;   // wave col offset in tile

  // staging: thread t loads 16B; row = t/4, col8 = (t%4)*8  (2 row-groups)
  const int srow = tid >> 2;
  const int scol = (tid & 3) * 8;
  const _Float16* ga = A + (long)(brow + srow) * lda + scol;
  const _Float16* gb = B + (long)(bcol + srow) * ldb + scol;
  _Float16* lA0 = As + wave * 512;         // rows 0..63   (wave*1024 bytes)
  _Float16* lA1 = As + 2048 + wave * 512;  // rows 64..127
  _Float16* lB0 = Bs + wave * 512;
  _Float16* lB1 = Bs + 2048 + wave * 512;
  const long a64 = (long)64 * lda;
  const long b64 = (long)64 * ldb;

  f32x4 acc[4][4];
#pragma unroll
  for (int m = 0; m < 4; ++m)
#pragma unroll
    for (int n = 0; n < 4; ++n) acc[m][n] = f32x4{0.f, 0.f, 0.f, 0.f};

  const int fr = lane & 15;        // row(A frag) / col(B frag) within 16
  const int fk = (lane >> 4) * 8;  // k offset within 32

  for (int k0 = 0; k0 < K; k0 += 32) {
    load_lds16(ga, lA0);
    load_lds16(ga + a64, lA1);
    load_lds16(gb, lB0);
    load_lds16(gb + b64, lB1);
    ga += 32;
    gb += 32;
    __syncthreads();  // drains vmcnt -> LDS tiles ready
    half8 af[4], bfv[4];
#pragma unroll
    for (int m = 0; m < 4; ++m)
      af[m] = *(const half8*)&As[(wr + m * 16 + fr) * 32 + fk];
#pragma unroll
    for (int n = 0; n < 4; ++n)
      bfv[n] = *(const half8*)&Bs[(wc + n * 16 + fr) * 32 + fk];
#pragma unroll
    for (int m = 0; m < 4; ++m)
#pragma unroll
      for (int n = 0; n < 4; ++n)
        acc[m][n] = __builtin_amdgcn_mfma_f32_16x16x32_f16(af[m], bfv[n],
                                                           acc[m][n], 0, 0, 0);
    __syncthreads();  // all reads done before next stage
  }

  // epilogue: D element r -> row = 4*(lane>>4)+r, col = lane&15  (verified map)
  const int r0 = (lane >> 4) * 4;
  const float* rs = nullptr;
  if constexpr (EPI == 4) rs = rsum + (long)z * rsZ;
#pragma unroll
  for (int m = 0; m < 4; ++m) {
    const int rowb = brow + wr + m * 16 + r0;
#pragma unroll
    for (int n = 0; n < 4; ++n) {
      const int col = bcol + wc + n * 16 + fr;
      float bsv = 0.f;
      if constexpr (EPI == 0 || EPI == 1 || EPI == 2 || EPI == 5) {
        if (bias) bsv = bias[col];
      }
#pragma unroll
      for (int r = 0; r < 4; ++r) {
        const long rr = rowb + r;
        const long ci = (long)z * cZ + rr * ldc + col;
        const float v = acc[m][n][r];
        if constexpr (EPI == 0) {
          ((float*)Cv)[ci] = v + bsv;
        } else if constexpr (EPI == 1) {
          ((_Float16*)Cv)[ci] = (_Float16)(v + bsv);
        } else if constexpr (EPI == 2) {
          ((_Float16*)Cv)[ci] = (_Float16)tanhf(v + bsv);
        } else if constexpr (EPI == 3) {
          ((_Float16*)Cv)[ci] = (_Float16)expf(v * scale);
        } else if constexpr (EPI == 4) {
          ((float*)Cv)[ci] = v / (rs[rr] + 1e-10f);
        } else if constexpr (EPI == 5) {
          ((float*)Cv)[ci] = tanhf(v + bsv);
        }
      }
    }
  }
}

// --------------------------- aux kernels -----------------------------------

__global__ __launch_bounds__(256) void cvt_f32_f16(const float* __restrict__ s,
                                                   _Float16* __restrict__ d,
                                                   long n) {
  const long i = ((long)blockIdx.x * 256 + threadIdx.x) * 8;
  if (i + 8 > n) return;
  const float4 a = *(const float4*)(s + i);
  const float4 b = *(const float4*)(s + i + 4);
  half8 o;
  o[0] = (_Float16)a.x; o[1] = (_Float16)a.y; o[2] = (_Float16)a.z; o[3] = (_Float16)a.w;
  o[4] = (_Float16)b.x; o[5] = (_Float16)b.y; o[6] = (_Float16)b.z; o[7] = (_Float16)b.w;
  *(half8*)(d + i) = o;
}

// dst[c][r] = (f16) src[r][c]   (R, C multiples of 32)
__global__ __launch_bounds__(256) void transpose_cast_f32_f16(
    const float* __restrict__ src, _Float16* __restrict__ dst, int R, int C) {
  __shared__ float tile[32][33];
  const int bx = blockIdx.x * 32, by = blockIdx.y * 32;
  const int tx = threadIdx.x & 31, ty = threadIdx.x >> 5;
#pragma unroll
  for (int i = 0; i < 32; i += 8)
    tile[ty + i][tx] = src[(long)(by + ty + i) * C + bx + tx];
  __syncthreads();
#pragma unroll
  for (int i = 0; i < 32; i += 8)
    dst[(long)(bx + ty + i) * R + by + tx] = (_Float16)tile[tx][ty + i];
}

__global__ __launch_bounds__(256) void transpose_f16(
    const _Float16* __restrict__ src, _Float16* __restrict__ dst, int R, int C) {
  __shared__ _Float16 tile[32][33];
  const int bx = blockIdx.x * 32, by = blockIdx.y * 32;
  const int tx = threadIdx.x & 31, ty = threadIdx.x >> 5;
#pragma unroll
  for (int i = 0; i < 32; i += 8)
    tile[ty + i][tx] = src[(long)(by + ty + i) * C + bx + tx];
  __syncthreads();
#pragma unroll
  for (int i = 0; i < 32; i += 8)
    dst[(long)(bx + ty + i) * R + by + tx] = tile[tx][ty + i];
}

// per-(row,head) L2 normalization over d=512, for q,k,v at once (grid.y=0,1,2)
__global__ __launch_bounds__(256) void l2norm_heads(
    const _Float16* __restrict__ q, const _Float16* __restrict__ k,
    const _Float16* __restrict__ v, _Float16* __restrict__ qn,
    _Float16* __restrict__ kn, _Float16* __restrict__ vn) {
  const long row = blockIdx.x;
  const _Float16* src = (blockIdx.y == 0) ? q : (blockIdx.y == 1) ? k : v;
  _Float16* dst = (blockIdx.y == 0) ? qn : (blockIdx.y == 1) ? kn : vn;
  src += row * 2048;
  dst += row * 2048;
  const int t = threadIdx.x, lane = t & 63, wv = t >> 6;
  __shared__ float sred[4];
#pragma unroll
  for (int h = 0; h < 4; ++h) {
    const int base = h * 512 + t * 2;
    const float fa = (float)src[base];
    const float fb = (float)src[base + 1];
    float s = fa * fa + fb * fb;
#pragma unroll
    for (int off = 1; off < 64; off <<= 1) s += __shfl_xor(s, off);
    if (lane == 0) sred[wv] = s;
    __syncthreads();
    const float tot = sred[0] + sred[1] + sred[2] + sred[3];
    const float rsc = rsqrtf(tot + 1e-10f);
    dst[base] = (_Float16)(fa * rsc);
    dst[base + 1] = (_Float16)(fb * rsc);
    __syncthreads();
  }
}

__global__ __launch_bounds__(256) void row_sum_f16(
    const _Float16* __restrict__ p, float* __restrict__ rs) {
  const long row = blockIdx.x;
  const _Float16* src = p + row * 2048;
  const int t = threadIdx.x, lane = t & 63, wv = t >> 6;
  const half8 d = *(const half8*)(src + t * 8);
  float s = 0.f;
#pragma unroll
  for (int i = 0; i < 8; ++i) s += (float)d[i];
#pragma unroll
  for (int off = 1; off < 64; off <<= 1) s += __shfl_xor(s, off);
  __shared__ float sred[4];
  if (lane == 0) sred[wv] = s;
  __syncthreads();
  if (t == 0) rs[row] = sred[0] + sred[1] + sred[2] + sred[3];
}

__global__ __launch_bounds__(256) void layernorm_f16(
    const float* __restrict__ a, const float* __restrict__ g,
    const float* __restrict__ b, _Float16* __restrict__ y) {
  const long row = blockIdx.x;
  const float* src = a + row * 2048;
  const int t = threadIdx.x, lane = t & 63, wv = t >> 6;
  const float4 v0 = *(const float4*)(src + t * 8);
  const float4 v1 = *(const float4*)(src + t * 8 + 4);
  float vals[8] = {v0.x, v0.y, v0.z, v0.w, v1.x, v1.y, v1.z, v1.w};
  float s = 0.f;
#pragma unroll
  for (int i = 0; i < 8; ++i) s += vals[i];
#pragma unroll
  for (int off = 1; off < 64; off <<= 1) s += __shfl_xor(s, off);
  __shared__ float sr1[4], sr2[4];
  if (lane == 0) sr1[wv] = s;
  __syncthreads();
  const float mu = (sr1[0] + sr1[1] + sr1[2] + sr1[3]) * (1.f / 2048.f);
  float d2 = 0.f;
#pragma unroll
  for (int i = 0; i < 8; ++i) {
    const float dd = vals[i] - mu;
    d2 += dd * dd;
  }
#pragma unroll
  for (int off = 1; off < 64; off <<= 1) d2 += __shfl_xor(d2, off);
  if (lane == 0) sr2[wv] = d2;
  __syncthreads();
  const float var = (sr2[0] + sr2[1] + sr2[2] + sr2[3]) * (1.f / 2048.f);
  const float inv = rsqrtf(var + 1e-5f);
#pragma unroll
  for (int i = 0; i < 8; ++i) {
    const int col = t * 8 + i;
    y[row * 2048 + col] = (_Float16)(g[col] * (vals[i] - mu) * inv + b[col]);
  }
}

// ---------------------------------------------------------------------------

extern "C" void kernel_launch(void* const* d_in, const int* in_sizes, int n_in,
                              void* d_out, int out_size, void* d_ws,
                              size_t ws_size, hipStream_t stream) {
  (void)in_sizes; (void)n_in; (void)out_size; (void)ws_size;
  const float* x = (const float*)d_in[0];    // [2048,1024]
  const float* We = (const float*)d_in[1];   // [1024,2048]
  const float* be = (const float*)d_in[2];
  const float* Wq = (const float*)d_in[3];   // [1024,2048]
  const float* bq = (const float*)d_in[4];
  const float* Wk = (const float*)d_in[5];   // [2048,2048]
  const float* bk = (const float*)d_in[6];
  const float* Wv = (const float*)d_in[7];   // [2048,2048]
  const float* bv = (const float*)d_in[8];
  const float* lng = (const float*)d_in[9];
  const float* lnb = (const float*)d_in[10];
  const float* Wd = (const float*)d_in[11];  // [2048,1024]
  const float* bd = (const float*)d_in[12];

  float* out = (float*)d_out;                       // [2048,1024]
  float* corr = out + (size_t)2048 * 1024;          // [4,2048,2048]

  char* w = (char*)d_ws;
  auto alloc = [&](size_t nbytes) -> void* {
    void* p = (void*)w;
    w += (nbytes + 255) & ~(size_t)255;
    return p;
  };
  _Float16* xh  = (_Float16*)alloc((size_t)2048 * 1024 * 2);
  _Float16* WeT = (_Float16*)alloc((size_t)2048 * 1024 * 2);  // [L=2048][S=1024]
  _Float16* WqT = (_Float16*)alloc((size_t)2048 * 1024 * 2);
  _Float16* WkT = (_Float16*)alloc((size_t)2048 * 2048 * 2);
  _Float16* WvT = (_Float16*)alloc((size_t)2048 * 2048 * 2);
  _Float16* WdT = (_Float16*)alloc((size_t)1024 * 2048 * 2);  // [S=1024][L=2048]
  _Float16* hh  = (_Float16*)alloc((size_t)2048 * 2048 * 2);
  _Float16* qh  = (_Float16*)alloc((size_t)2048 * 2048 * 2);
  _Float16* kh  = (_Float16*)alloc((size_t)2048 * 2048 * 2);
  _Float16* vh  = (_Float16*)alloc((size_t)2048 * 2048 * 2);
  _Float16* qn  = (_Float16*)alloc((size_t)2048 * 2048 * 2);
  _Float16* kn  = (_Float16*)alloc((size_t)2048 * 2048 * 2);
  _Float16* vn  = (_Float16*)alloc((size_t)2048 * 2048 * 2);
  _Float16* vT  = (_Float16*)alloc((size_t)2048 * 2048 * 2);  // [L][N]
  _Float16* ph  = (_Float16*)alloc((size_t)4 * 2048 * 2048 * 2);
  float* rsum   = (float*)alloc((size_t)4 * 2048 * 4);
  float* af     = (float*)alloc((size_t)2048 * 2048 * 4);
  _Float16* yh  = (_Float16*)alloc((size_t)2048 * 2048 * 2);

  const dim3 blk(256);
  const long NN = (long)2048 * 2048;

  // 0. conversions / weight transposes
  cvt_f32_f16<<<dim3(1024), blk, 0, stream>>>(x, xh, (long)2048 * 1024);
  transpose_cast_f32_f16<<<dim3(64, 32), blk, 0, stream>>>(We, WeT, 1024, 2048);
  transpose_cast_f32_f16<<<dim3(64, 32), blk, 0, stream>>>(Wq, WqT, 1024, 2048);
  transpose_cast_f32_f16<<<dim3(64, 64), blk, 0, stream>>>(Wk, WkT, 2048, 2048);
  transpose_cast_f32_f16<<<dim3(64, 64), blk, 0, stream>>>(Wv, WvT, 2048, 2048);
  transpose_cast_f32_f16<<<dim3(32, 64), blk, 0, stream>>>(Wd, WdT, 2048, 1024);

  // 1. h = tanh(x @ We + be)
  gemm_nt<2><<<dim3(16, 16, 1), blk, 0, stream>>>(
      xh, WeT, hh, 1024, 1024, 1024, 2048, 0, 0, 0, be, 0.f, nullptr, 0);
  // 2. q, k, v
  gemm_nt<1><<<dim3(16, 16, 1), blk, 0, stream>>>(
      xh, WqT, qh, 1024, 1024, 1024, 2048, 0, 0, 0, bq, 0.f, nullptr, 0);
  gemm_nt<1><<<dim3(16, 16, 1), blk, 0, stream>>>(
      hh, WkT, kh, 2048, 2048, 2048, 2048, 0, 0, 0, bk, 0.f, nullptr, 0);
  gemm_nt<1><<<dim3(16, 16, 1), blk, 0, stream>>>(
      hh, WvT, vh, 2048, 2048, 2048, 2048, 0, 0, 0, bv, 0.f, nullptr, 0);
  // 3. per-head norms + v transpose
  l2norm_heads<<<dim3(2048, 3), blk, 0, stream>>>(qh, kh, vh, qn, kn, vn);
  transpose_f16<<<dim3(64, 64), blk, 0, stream>>>(vh, vT, 2048, 2048);
  // 4. p = exp(scale * qn·kn^T)   (heads batched via grid.z)
  const float scl = 1.0f / sqrtf(512.f);
  gemm_nt<3><<<dim3(16, 16, 4), blk, 0, stream>>>(
      qn, kn, ph, 512, 2048, 2048, 2048, 512, 512, NN, nullptr, scl, nullptr, 0);
  // 5. rowsum + a = (p @ v)/rowsum  (written into concat layout [N, 2048])
  row_sum_f16<<<dim3(8192), blk, 0, stream>>>(ph, rsum);
  gemm_nt<4><<<dim3(4, 16, 4), blk, 0, stream>>>(
      ph, vT, af, 2048, 2048, 2048, 2048, NN, (long)512 * 2048, 512, nullptr,
      0.f, rsum, 2048);
  // 6. LayerNorm + decode
  layernorm_f16<<<dim3(2048), blk, 0, stream>>>(af, lng, lnb, yh);
  gemm_nt<5><<<dim3(8, 16, 1), blk, 0, stream>>>(
      yh, WdT, out, 2048, 2048, 2048, 1024, 0, 0, 0, bd, 0.f, nullptr, 0);
  // 7. corr = kn @ vn^T
  gemm_nt<0><<<dim3(16, 16, 4), blk, 0, stream>>>(
      kn, vn, corr, 512, 2048, 2048, 2048, 512, 512, NN, nullptr, 0.f, nullptr, 0);
}

// Round 4
// 406.167 us; speedup vs baseline: 1.3016x; 1.3016x over previous
//
#include <hip/hip_runtime.h>
#include <cmath>
#include <cstdint>

// ---------------------------------------------------------------------------
// Plasmodium attention block on MI355X (gfx950).
// All matmuls fp16-MFMA (16x16x32), f32 accumulate, NT layout, 2-phase
// double-buffered pipeline (issue next global_load_lds before MFMA of cur).
//   1. [HQ z=2]  h = tanh(x@We+be); q = x@Wq+bq  (+ row sumsq(q) atomics)
//   2. [KV z=2]  k = h@Wk+bk; v = h@Wv+bv        (+ row sumsq(k),(v) atomics)
//   3. vT transpose
//   4. [P  z=4]  p = exp(scale * (q.kT) * rsq_q[i] * rsq_k[j])  f16
//                (+ row-sum(p) atomics; max-subtraction provably unnecessary:
//                 |scores|<=1/sqrt(512), row factor cancels in p.v/sum(p))
//   5. [PV z=4]  a = (p@vT rows)/(rowsum+eps) -> concat heads  f32
//   6. LayerNorm -> f16;  [DEC] out = tanh(y@Wd+bd) f32
//   7. [CORR z=4] corr = (k.vT) * rsq_k[i] * rsq_v[j]  f32
// ---------------------------------------------------------------------------

typedef __attribute__((ext_vector_type(8))) _Float16 half8;
typedef __attribute__((ext_vector_type(4))) float f32x4;

typedef __attribute__((address_space(1))) void GV;  // global
typedef __attribute__((address_space(3))) void LV;  // LDS

__device__ __forceinline__ void load_lds16(const _Float16* g, _Float16* l) {
  // dest = wave-uniform base + lane*16B (HW semantic); src is per-lane.
  __builtin_amdgcn_global_load_lds((GV*)g, (LV*)l, 16, 0, 0);
}

// ---------------------------------------------------------------------------
// NT GEMM: C[i,j] = sum_k A[i,k]*B[j,k].  BM x BN tile, BK=32, 4 waves (2x2).
// EPI 0: HQ   z0: f16 tanh(acc+bias0)        z1: f16 acc+bias1, sumsq->redOut
// EPI 1: KV   f16 acc+bias(z), sumsq->redOut + z*8192
// EPI 2: P    f16 exp(acc*scale*ri*rj), rowsum->redOut + z*2048
// EPI 3: PV   f32 acc/(rowIn[row]+eps)
// EPI 4: DEC  f32 tanh(acc+bias0)
// EPI 5: CORR f32 acc*ri*rj
// ---------------------------------------------------------------------------
template <int EPI, int BM, int BN>
__global__ __launch_bounds__(256) void gemm_nt(
    const _Float16* __restrict__ A, const _Float16* __restrict__ B,
    void* __restrict__ Cv, int K, int lda, int ldb, int ldc,
    long aZ, long bZ, long cZ,
    const float* __restrict__ bias0, const float* __restrict__ bias1,
    float scale, const float* __restrict__ rowIn,
    const float* __restrict__ colIn, float* __restrict__ redOut) {
  constexpr int MR = BM / 32, NR = BN / 32;
  __shared__ _Float16 As[2][BM * 32];
  __shared__ _Float16 Bs[2][BN * 32];

  const int z = blockIdx.z;
  A += (long)z * aZ;
  B += (long)z * bZ;

  const int tid = threadIdx.x;
  const int wave = tid >> 6;
  const int lane = tid & 63;
  const int brow = blockIdx.y * BM;
  const int bcol = blockIdx.x * BN;
  const int wr = (wave >> 1) * (BM / 2);
  const int wc = (wave & 1) * (BN / 2);

  // staging: thread t loads 16B; row = t>>2, col8 = (t&3)*8  (64 rows/issue)
  const int srow = tid >> 2;
  const int scol = (tid & 3) * 8;
  const _Float16* ga = A + (long)(brow + srow) * lda + scol;
  const _Float16* gb = B + (long)(bcol + srow) * ldb + scol;
  const long a64 = (long)64 * lda;
  const long b64 = (long)64 * ldb;
  const int lofs = wave * 512;  // wave w covers rows 16w..16w+15 (512 halfs)

  f32x4 acc[MR][NR];
#pragma unroll
  for (int m = 0; m < MR; ++m)
#pragma unroll
    for (int n = 0; n < NR; ++n) acc[m][n] = f32x4{0.f, 0.f, 0.f, 0.f};

  const int fr = lane & 15;        // row(A frag)/col(B frag) within 16
  const int fk = (lane >> 4) * 8;  // k offset within 32
  const int nt = K >> 5;

  // prologue: stage tile 0 -> buf 0
  load_lds16(ga, &As[0][lofs]);
  if constexpr (BM == 128) load_lds16(ga + a64, &As[0][2048 + lofs]);
  load_lds16(gb, &Bs[0][lofs]);
  if constexpr (BN == 128) load_lds16(gb + b64, &Bs[0][2048 + lofs]);

  for (int t = 0; t < nt; ++t) {
    const int cur = t & 1;
    __syncthreads();  // vmcnt(0): buf[cur] staged; lgkm: buf[cur^1] reads done
    if (t + 1 < nt) {  // issue next tile into other buffer (overlaps MFMA)
      const int ko = (t + 1) << 5;
      const int nb = cur ^ 1;
      load_lds16(ga + ko, &As[nb][lofs]);
      if constexpr (BM == 128) load_lds16(ga + ko + a64, &As[nb][2048 + lofs]);
      load_lds16(gb + ko, &Bs[nb][lofs]);
      if constexpr (BN == 128) load_lds16(gb + ko + b64, &Bs[nb][2048 + lofs]);
    }
    half8 af[MR], bf[NR];
#pragma unroll
    for (int m = 0; m < MR; ++m)
      af[m] = *(const half8*)&As[cur][(wr + m * 16 + fr) * 32 + fk];
#pragma unroll
    for (int n = 0; n < NR; ++n)
      bf[n] = *(const half8*)&Bs[cur][(wc + n * 16 + fr) * 32 + fk];
#pragma unroll
    for (int m = 0; m < MR; ++m)
#pragma unroll
      for (int n = 0; n < NR; ++n)
        acc[m][n] = __builtin_amdgcn_mfma_f32_16x16x32_f16(af[m], bf[n],
                                                           acc[m][n], 0, 0, 0);
  }

  // epilogue: D elem r -> row = wr+m*16+(lane>>4)*4+r, col = wc+n*16+(lane&15)
  const int r0 = (lane >> 4) * 4;

  if constexpr (EPI == 0 || EPI == 1) {
    const float* bs = (z == 0) ? bias0 : bias1;
    _Float16* C = (_Float16*)Cv + (long)z * cZ;
    float ss[MR][4];
#pragma unroll
    for (int m = 0; m < MR; ++m)
#pragma unroll
      for (int r = 0; r < 4; ++r) ss[m][r] = 0.f;
#pragma unroll
    for (int m = 0; m < MR; ++m)
#pragma unroll
      for (int n = 0; n < NR; ++n) {
        const int col = bcol + wc + n * 16 + fr;
        const float bv = bs[col];
#pragma unroll
        for (int r = 0; r < 4; ++r) {
          const int row = brow + wr + m * 16 + r0 + r;
          const float val = acc[m][n][r] + bv;
          if (EPI == 0 && z == 0) {
            C[(long)row * ldc + col] = (_Float16)tanhf(val);
          } else {
            C[(long)row * ldc + col] = (_Float16)val;
            ss[m][r] += val * val;
          }
        }
      }
    if (EPI == 1 || z == 1) {
      const int head = (bcol + wc) >> 9;  // wave spans <=64 cols, 64 | 512
      float* sq = redOut + (EPI == 1 ? z * 8192 : 0) + head * 2048;
#pragma unroll
      for (int m = 0; m < MR; ++m)
#pragma unroll
        for (int r = 0; r < 4; ++r) {
          float s = ss[m][r];
          s += __shfl_xor(s, 1);
          s += __shfl_xor(s, 2);
          s += __shfl_xor(s, 4);
          s += __shfl_xor(s, 8);
          if (fr == 0) atomicAdd(&sq[brow + wr + m * 16 + r0 + r], s);
        }
    }
  } else if constexpr (EPI == 2) {
    _Float16* C = (_Float16*)Cv + (long)z * cZ;
    const float* sA = rowIn + z * 2048;
    const float* sB = colIn + z * 2048;
    float rj[NR];
#pragma unroll
    for (int n = 0; n < NR; ++n)
      rj[n] = rsqrtf(sB[bcol + wc + n * 16 + fr] + 1e-10f);
    float rowacc[MR][4];
#pragma unroll
    for (int m = 0; m < MR; ++m)
#pragma unroll
      for (int r = 0; r < 4; ++r) {
        const int row = brow + wr + m * 16 + r0 + r;
        const float ri = rsqrtf(sA[row] + 1e-10f) * scale;
        float ra = 0.f;
#pragma unroll
        for (int n = 0; n < NR; ++n) {
          const int col = bcol + wc + n * 16 + fr;
          const float val = expf(acc[m][n][r] * ri * rj[n]);
          C[(long)row * ldc + col] = (_Float16)val;
          ra += val;
        }
        rowacc[m][r] = ra;
      }
    float* rs = redOut + z * 2048;
#pragma unroll
    for (int m = 0; m < MR; ++m)
#pragma unroll
      for (int r = 0; r < 4; ++r) {
        float s = rowacc[m][r];
        s += __shfl_xor(s, 1);
        s += __shfl_xor(s, 2);
        s += __shfl_xor(s, 4);
        s += __shfl_xor(s, 8);
        if (fr == 0) atomicAdd(&rs[brow + wr + m * 16 + r0 + r], s);
      }
  } else if constexpr (EPI == 3) {
    float* C = (float*)Cv + (long)z * cZ;
    const float* rs = rowIn + z * 2048;
#pragma unroll
    for (int m = 0; m < MR; ++m)
#pragma unroll
      for (int r = 0; r < 4; ++r) {
        const int row = brow + wr + m * 16 + r0 + r;
        const float inv = 1.f / (rs[row] + 1e-10f);
#pragma unroll
        for (int n = 0; n < NR; ++n) {
          const int col = bcol + wc + n * 16 + fr;
          C[(long)row * ldc + col] = acc[m][n][r] * inv;
        }
      }
  } else if constexpr (EPI == 4) {
    float* C = (float*)Cv;
#pragma unroll
    for (int m = 0; m < MR; ++m)
#pragma unroll
      for (int n = 0; n < NR; ++n) {
        const int col = bcol + wc + n * 16 + fr;
        const float bv = bias0[col];
#pragma unroll
        for (int r = 0; r < 4; ++r) {
          const int row = brow + wr + m * 16 + r0 + r;
          C[(long)row * ldc + col] = tanhf(acc[m][n][r] + bv);
        }
      }
  } else if constexpr (EPI == 5) {
    float* C = (float*)Cv + (long)z * cZ;
    const float* sA = rowIn + z * 2048;
    const float* sB = colIn + z * 2048;
    float rj[NR];
#pragma unroll
    for (int n = 0; n < NR; ++n)
      rj[n] = rsqrtf(sB[bcol + wc + n * 16 + fr] + 1e-10f);
#pragma unroll
    for (int m = 0; m < MR; ++m)
#pragma unroll
      for (int r = 0; r < 4; ++r) {
        const int row = brow + wr + m * 16 + r0 + r;
        const float ri = rsqrtf(sA[row] + 1e-10f);
#pragma unroll
        for (int n = 0; n < NR; ++n) {
          const int col = bcol + wc + n * 16 + fr;
          C[(long)row * ldc + col] = acc[m][n][r] * ri * rj[n];
        }
      }
  }
}

// --------------------------- aux kernels -----------------------------------

__global__ __launch_bounds__(256) void cvt_f32_f16(const float* __restrict__ s,
                                                   _Float16* __restrict__ d,
                                                   long n) {
  const long i = ((long)blockIdx.x * 256 + threadIdx.x) * 8;
  if (i + 8 > n) return;
  const float4 a = *(const float4*)(s + i);
  const float4 b = *(const float4*)(s + i + 4);
  half8 o;
  o[0] = (_Float16)a.x; o[1] = (_Float16)a.y; o[2] = (_Float16)a.z; o[3] = (_Float16)a.w;
  o[4] = (_Float16)b.x; o[5] = (_Float16)b.y; o[6] = (_Float16)b.z; o[7] = (_Float16)b.w;
  *(half8*)(d + i) = o;
}

// dst[z][c][r] = (f16) src_z[r][c]; src selected by blockIdx.z
__global__ __launch_bounds__(256) void transpose_cast2(
    const float* __restrict__ s0, const float* __restrict__ s1,
    _Float16* __restrict__ d, int R, int C) {
  __shared__ float tile[32][33];
  const float* src = blockIdx.z ? s1 : s0;
  _Float16* dst = d + (size_t)blockIdx.z * R * C;
  const int bx = blockIdx.x * 32, by = blockIdx.y * 32;
  const int tx = threadIdx.x & 31, ty = threadIdx.x >> 5;
#pragma unroll
  for (int i = 0; i < 32; i += 8)
    tile[ty + i][tx] = src[(long)(by + ty + i) * C + bx + tx];
  __syncthreads();
#pragma unroll
  for (int i = 0; i < 32; i += 8)
    dst[(long)(bx + ty + i) * R + by + tx] = (_Float16)tile[tx][ty + i];
}

__global__ __launch_bounds__(256) void transpose_f16(
    const _Float16* __restrict__ src, _Float16* __restrict__ dst, int R, int C) {
  __shared__ _Float16 tile[32][33];
  const int bx = blockIdx.x * 32, by = blockIdx.y * 32;
  const int tx = threadIdx.x & 31, ty = threadIdx.x >> 5;
#pragma unroll
  for (int i = 0; i < 32; i += 8)
    tile[ty + i][tx] = src[(long)(by + ty + i) * C + bx + tx];
  __syncthreads();
#pragma unroll
  for (int i = 0; i < 32; i += 8)
    dst[(long)(bx + ty + i) * R + by + tx] = tile[tx][ty + i];
}

__global__ __launch_bounds__(256) void layernorm_f16(
    const float* __restrict__ a, const float* __restrict__ g,
    const float* __restrict__ b, _Float16* __restrict__ y) {
  const long row = blockIdx.x;
  const float* src = a + row * 2048;
  const int t = threadIdx.x, lane = t & 63, wv = t >> 6;
  const float4 v0 = *(const float4*)(src + t * 8);
  const float4 v1 = *(const float4*)(src + t * 8 + 4);
  float vals[8] = {v0.x, v0.y, v0.z, v0.w, v1.x, v1.y, v1.z, v1.w};
  float s = 0.f;
#pragma unroll
  for (int i = 0; i < 8; ++i) s += vals[i];
#pragma unroll
  for (int off = 1; off < 64; off <<= 1) s += __shfl_xor(s, off);
  __shared__ float sr1[4], sr2[4];
  if (lane == 0) sr1[wv] = s;
  __syncthreads();
  const float mu = (sr1[0] + sr1[1] + sr1[2] + sr1[3]) * (1.f / 2048.f);
  float d2 = 0.f;
#pragma unroll
  for (int i = 0; i < 8; ++i) {
    const float dd = vals[i] - mu;
    d2 += dd * dd;
  }
#pragma unroll
  for (int off = 1; off < 64; off <<= 1) d2 += __shfl_xor(d2, off);
  if (lane == 0) sr2[wv] = d2;
  __syncthreads();
  const float var = (sr2[0] + sr2[1] + sr2[2] + sr2[3]) * (1.f / 2048.f);
  const float inv = rsqrtf(var + 1e-5f);
#pragma unroll
  for (int i = 0; i < 8; ++i) {
    const int col = t * 8 + i;
    y[row * 2048 + col] = (_Float16)(g[col] * (vals[i] - mu) * inv + b[col]);
  }
}

// ---------------------------------------------------------------------------

extern "C" void kernel_launch(void* const* d_in, const int* in_sizes, int n_in,
                              void* d_out, int out_size, void* d_ws,
                              size_t ws_size, hipStream_t stream) {
  (void)in_sizes; (void)n_in; (void)out_size; (void)ws_size;
  const float* x = (const float*)d_in[0];    // [2048,1024]
  const float* We = (const float*)d_in[1];   // [1024,2048]
  const float* be = (const float*)d_in[2];
  const float* Wq = (const float*)d_in[3];   // [1024,2048]
  const float* bq = (const float*)d_in[4];
  const float* Wk = (const float*)d_in[5];   // [2048,2048]
  const float* bk = (const float*)d_in[6];
  const float* Wv = (const float*)d_in[7];   // [2048,2048]
  const float* bv = (const float*)d_in[8];
  const float* lng = (const float*)d_in[9];
  const float* lnb = (const float*)d_in[10];
  const float* Wd = (const float*)d_in[11];  // [2048,1024]
  const float* bd = (const float*)d_in[12];

  float* out = (float*)d_out;               // [2048,1024]
  float* corr = out + (size_t)2048 * 1024;  // [4,2048,2048]

  char* w = (char*)d_ws;
  auto alloc = [&](size_t nbytes) -> void* {
    void* p = (void*)w;
    w += (nbytes + 255) & ~(size_t)255;
    return p;
  };
  const long NN = (long)2048 * 2048;
  _Float16* xh  = (_Float16*)alloc((size_t)2048 * 1024 * 2);
  _Float16* WeT = (_Float16*)alloc((size_t)2048 * 1024 * 2);  // adj WqT
  _Float16* WqT = (_Float16*)alloc((size_t)2048 * 1024 * 2);
  _Float16* WkT = (_Float16*)alloc((size_t)2048 * 2048 * 2);  // adj WvT
  _Float16* WvT = (_Float16*)alloc((size_t)2048 * 2048 * 2);
  _Float16* WdT = (_Float16*)alloc((size_t)1024 * 2048 * 2);
  _Float16* hh  = (_Float16*)alloc((size_t)NN * 2);           // adj qh
  _Float16* qh  = (_Float16*)alloc((size_t)NN * 2);
  _Float16* kh  = (_Float16*)alloc((size_t)NN * 2);           // adj vh
  _Float16* vh  = (_Float16*)alloc((size_t)NN * 2);
  _Float16* vT  = (_Float16*)alloc((size_t)NN * 2);           // [L][N]
  _Float16* ph  = (_Float16*)alloc((size_t)4 * NN * 2);
  float* stats  = (float*)alloc((size_t)4 * 8192 * 4);  // sqQ,sqK,sqV,rsum
  float* af     = (float*)alloc((size_t)NN * 4);
  _Float16* yh  = (_Float16*)alloc((size_t)NN * 2);
  float* sqQ = stats;
  float* sqK = stats + 8192;
  float* sqV = stats + 16384;
  float* rsum = stats + 24576;

  const dim3 blk(256);

  // 0. conversions / weight transposes / stats zero-init
  cvt_f32_f16<<<dim3(1024), blk, 0, stream>>>(x, xh, (long)2048 * 1024);
  transpose_cast2<<<dim3(64, 32, 2), blk, 0, stream>>>(We, Wq, WeT, 1024, 2048);
  transpose_cast2<<<dim3(64, 64, 2), blk, 0, stream>>>(Wk, Wv, WkT, 2048, 2048);
  transpose_cast2<<<dim3(32, 64, 1), blk, 0, stream>>>(Wd, Wd, WdT, 2048, 1024);
  hipMemsetAsync(stats, 0, (size_t)4 * 8192 * 4, stream);

  // 1. h = tanh(x@We+be), q = x@Wq+bq (+sumsq q)
  gemm_nt<0, 128, 64><<<dim3(32, 16, 2), blk, 0, stream>>>(
      xh, WeT, hh, 1024, 1024, 1024, 2048, 0L, (long)2048 * 1024, NN,
      be, bq, 0.f, nullptr, nullptr, sqQ);
  // 2. k = h@Wk+bk, v = h@Wv+bv (+sumsq k,v)
  gemm_nt<1, 128, 64><<<dim3(32, 16, 2), blk, 0, stream>>>(
      hh, WkT, kh, 2048, 2048, 2048, 2048, 0L, (long)2048 * 2048, NN,
      bk, bv, 0.f, nullptr, nullptr, sqK);
  // 3. vT
  transpose_f16<<<dim3(64, 64), blk, 0, stream>>>(vh, vT, 2048, 2048);
  // 4. p = exp(scale * q.kT * rq * rk)  (+rowsum)
  const float scl = 1.0f / sqrtf(512.f);
  gemm_nt<2, 128, 128><<<dim3(16, 16, 4), blk, 0, stream>>>(
      qh, kh, ph, 512, 2048, 2048, 2048, 512L, 512L, NN,
      nullptr, nullptr, scl, sqQ, sqK, rsum);
  // 5. a = (p@v)/(rowsum+eps)  -> concat-head layout [N,2048]
  gemm_nt<3, 128, 64><<<dim3(8, 16, 4), blk, 0, stream>>>(
      ph, vT, af, 2048, 2048, 2048, 2048, NN, (long)512 * 2048, 512L,
      nullptr, nullptr, 0.f, rsum, nullptr, nullptr);
  // 6. LayerNorm + decode
  layernorm_f16<<<dim3(2048), blk, 0, stream>>>(af, lng, lnb, yh);
  gemm_nt<4, 64, 64><<<dim3(16, 32, 1), blk, 0, stream>>>(
      yh, WdT, out, 2048, 2048, 2048, 1024, 0L, 0L, 0L,
      bd, nullptr, 0.f, nullptr, nullptr, nullptr);
  // 7. corr = k.vT * rk * rv
  gemm_nt<5, 128, 128><<<dim3(16, 16, 4), blk, 0, stream>>>(
      kh, vh, corr, 512, 2048, 2048, 2048, 512L, 512L, NN,
      nullptr, nullptr, 0.f, sqK, sqV, nullptr);
}